// Round 2
// baseline (739.108 us; speedup 1.0000x reference)
//
#include <hip/hip_runtime.h>
#include <math.h>

// VQ-VAE eval forward: argmin distances + one-hot + gather + loss + perplexity.
// inputs: [128,1024,64] fp32, embedding: [512,64] fp32
// out: loss[1] | quantized[8388608] | perplexity[1] | encodings[67108864]

#define NK 512
#define ND 64
#define NROWS 131072
#define ROWS_PER_BLOCK 256
#define NBLOCKS (NROWS / ROWS_PER_BLOCK)   // 512

#define Q_OFF    1
#define PERP_OFF 8388609
#define ENC_OFF  8388610

typedef float vfloat2 __attribute__((ext_vector_type(2)));

__global__ __launch_bounds__(256) void vq_main(const float* __restrict__ x,
                                               const float* __restrict__ emb,
                                               float* __restrict__ out,
                                               int* __restrict__ g_counts,
                                               float* __restrict__ g_loss) {
    extern __shared__ float smem[];
    float* e_lds   = smem;                       // 32768 floats (128 KB)
    float* eknorm  = e_lds + NK * ND;            // 512
    int*   argmin_s = (int*)(eknorm + NK);       // 256
    int*   hist     = argmin_s + ROWS_PER_BLOCK; // 512
    float* red      = (float*)(hist + NK);       // 4 wave partials

    const int tid = threadIdx.x;

    // ---- stage embedding into LDS (coalesced float4) ----
    {
        const float4* src = (const float4*)emb;
        float4* dst = (float4*)e_lds;
        for (int i = tid; i < NK * ND / 4; i += 256) dst[i] = src[i];
    }
    for (int i = tid; i < NK; i += 256) hist[i] = 0;
    __syncthreads();

    // ---- |e_k|^2 ----
    for (int k = tid; k < NK; k += 256) {
        const float4* er = (const float4*)(e_lds + k * ND);
        float s0 = 0.f, s1 = 0.f, s2 = 0.f, s3 = 0.f;
        #pragma unroll
        for (int j = 0; j < ND / 4; ++j) {
            float4 v = er[j];
            s0 += v.x * v.x; s1 += v.y * v.y; s2 += v.z * v.z; s3 += v.w * v.w;
        }
        eknorm[k] = (s0 + s1) + (s2 + s3);
    }
    __syncthreads();

    // ---- load my row into registers ----
    const int row = blockIdx.x * ROWS_PER_BLOCK + tid;
    float4 xr[16];
    const float4* xp = (const float4*)(x + (size_t)row * ND);
    #pragma unroll
    for (int j = 0; j < 16; ++j) xr[j] = xp[j];

    float xn0 = 0.f, xn1 = 0.f, xn2 = 0.f, xn3 = 0.f;
    #pragma unroll
    for (int j = 0; j < 16; ++j) {
        xn0 += xr[j].x * xr[j].x; xn1 += xr[j].y * xr[j].y;
        xn2 += xr[j].z * xr[j].z; xn3 += xr[j].w * xr[j].w;
    }
    const float xnorm = (xn0 + xn1) + (xn2 + xn3);

    // ---- argmin over 512 codes; dist = |e|^2 - 2 x.e (xnorm const per row) ----
    float dmin = INFINITY;
    int amin = 0;
    for (int k = 0; k < NK; k += 2) {
        const float4* e0 = (const float4*)(e_lds + k * ND);
        const float4* e1 = (const float4*)(e_lds + (k + 1) * ND);
        float a0 = 0.f, a1 = 0.f, a2 = 0.f, a3 = 0.f;
        float b0 = 0.f, b1 = 0.f, b2 = 0.f, b3 = 0.f;
        #pragma unroll
        for (int j = 0; j < 16; ++j) {
            float4 xv = xr[j];
            float4 v0 = e0[j];
            float4 v1 = e1[j];
            a0 += xv.x * v0.x; a1 += xv.y * v0.y; a2 += xv.z * v0.z; a3 += xv.w * v0.w;
            b0 += xv.x * v1.x; b1 += xv.y * v1.y; b2 += xv.z * v1.z; b3 += xv.w * v1.w;
        }
        float dot0 = (a0 + a1) + (a2 + a3);
        float dot1 = (b0 + b1) + (b2 + b3);
        float d0 = eknorm[k]     - 2.f * dot0;
        float d1 = eknorm[k + 1] - 2.f * dot1;
        if (d0 < dmin) { dmin = d0; amin = k; }       // strict <: first-index tie-break
        if (d1 < dmin) { dmin = d1; amin = k + 1; }
    }

    argmin_s[tid] = amin;
    atomicAdd(&hist[amin], 1);

    // ---- loss partial: |x - e_amin|^2 = xnorm + dmin ----
    float lossv = xnorm + dmin;
    #pragma unroll
    for (int off = 32; off >= 1; off >>= 1) lossv += __shfl_down(lossv, off);
    if ((tid & 63) == 0) red[tid >> 6] = lossv;
    __syncthreads();   // argmin_s, hist, red now visible

    if (tid == 0) atomicAdd(g_loss, (red[0] + red[1]) + (red[2] + red[3]));
    for (int i = tid; i < NK; i += 256) {
        int c = hist[i];
        if (c) atomicAdd(&g_counts[i], c);
    }

    // ---- quantized: coalesced dword stores (region starts at element 1: only 4B-aligned) ----
    {
        float* qout = out + Q_OFF + (size_t)blockIdx.x * ROWS_PER_BLOCK * ND;
        for (int p = tid; p < ROWS_PER_BLOCK * ND; p += 256) {
            int r = p >> 6;
            int c = p & 63;
            qout[p] = e_lds[argmin_s[r] * ND + c];
        }
    }

    // ---- encodings: one-hot rows, coalesced vfloat2 nontemporal stores (8B-aligned) ----
    {
        vfloat2* eout = (vfloat2*)(out + ENC_OFF + (size_t)blockIdx.x * ROWS_PER_BLOCK * NK);
        const int nf2 = ROWS_PER_BLOCK * NK / 2;   // 65536
        for (int p = tid; p < nf2; p += 256) {
            int r  = p >> 8;         // 256 vfloat2 per row
            int c2 = p & 255;
            int am = argmin_s[r];
            vfloat2 v = {0.f, 0.f};
            if ((am >> 1) == c2) {
                if (am & 1) v.y = 1.f; else v.x = 1.f;
            }
            __builtin_nontemporal_store(v, &eout[p]);
        }
    }
}

__global__ __launch_bounds__(512) void vq_final(const int* __restrict__ g_counts,
                                                const float* __restrict__ g_loss,
                                                float* __restrict__ out) {
    __shared__ float red[8];
    int t = threadIdx.x;
    float p = (float)g_counts[t] * (1.0f / (float)NROWS);
    float h = p * logf(p + 1e-10f);
    #pragma unroll
    for (int off = 32; off >= 1; off >>= 1) h += __shfl_down(h, off);
    if ((t & 63) == 0) red[t >> 6] = h;
    __syncthreads();
    if (t == 0) {
        float s = 0.f;
        #pragma unroll
        for (int i = 0; i < 8; ++i) s += red[i];
        out[PERP_OFF] = expf(-s);
        out[0] = 0.25f * g_loss[0] / (float)(NROWS * ND);
    }
}

extern "C" void kernel_launch(void* const* d_in, const int* in_sizes, int n_in,
                              void* d_out, int out_size, void* d_ws, size_t ws_size,
                              hipStream_t stream) {
    const float* x   = (const float*)d_in[0];
    const float* emb = (const float*)d_in[1];
    float* out = (float*)d_out;

    int*   g_counts = (int*)d_ws;
    float* g_loss   = (float*)((char*)d_ws + 2048);

    // ws is re-poisoned to 0xAA before every launch — zero our accumulators.
    (void)hipMemsetAsync(d_ws, 0, 4096, stream);

    // 128 KB embedding + norms + argmin + hist + reduce scratch (~133 KB < 160 KB/CU)
    size_t lds_bytes = (size_t)(NK * ND + NK) * 4 + ROWS_PER_BLOCK * 4 + NK * 4 + 16 * 4;
    (void)hipFuncSetAttribute((const void*)vq_main,
                              hipFuncAttributeMaxDynamicSharedMemorySize, (int)lds_bytes);

    vq_main<<<NBLOCKS, 256, lds_bytes, stream>>>(x, emb, out, g_counts, g_loss);
    vq_final<<<1, 512, 0, stream>>>(g_counts, g_loss, out);
}

// Round 3
// 598.545 us; speedup vs baseline: 1.2348x; 1.2348x over previous
//
#include <hip/hip_runtime.h>
#include <math.h>

// VQ-VAE eval forward: argmin distances + one-hot + gather + loss + perplexity.
// inputs: [128,1024,64] fp32, embedding: [512,64] fp32
// out: loss[1] | quantized[8388608] | perplexity[1] | encodings[67108864]
//
// R3: 1024-thread blocks (16 waves/CU, was 4). Codes split 4-way across thread
// quads (tile = tid>>8, 128 codes each); rows/block stays 256 (row = tid&255).
// Attacks the R2 bottleneck: OccupancyPercent 11.8% with a 133KB-LDS 256-thread
// block -> 1 block/CU, 4 waves. Now same LDS but 16 waves/CU.

#define NK 512
#define ND 64
#define NROWS 131072
#define ROWS_PER_BLOCK 256
#define NBLOCKS (NROWS / ROWS_PER_BLOCK)   // 512
#define BLOCK_T 1024

#define Q_OFF    1
#define PERP_OFF 8388609
#define ENC_OFF  8388610

typedef float vfloat2 __attribute__((ext_vector_type(2)));

__global__ __launch_bounds__(BLOCK_T) void vq_main(const float* __restrict__ x,
                                                   const float* __restrict__ emb,
                                                   float* __restrict__ out,
                                                   int* __restrict__ g_counts,
                                                   float* __restrict__ g_loss) {
    extern __shared__ float smem[];
    float* e_lds   = smem;                        // 32768 floats (128 KB)
    float* eknorm  = e_lds + NK * ND;             // 512
    float* cand_d  = eknorm + NK;                 // 4*256
    int*   cand_i  = (int*)(cand_d + 4 * 256);    // 4*256
    int*   argmin_s = cand_i + 4 * 256;           // 256
    int*   hist     = argmin_s + ROWS_PER_BLOCK;  // 512
    float* red      = (float*)(hist + NK);        // 4 wave partials (waves 0-3)

    const int tid  = threadIdx.x;
    const int r    = tid & 255;        // row within block
    const int tile = tid >> 8;         // code tile 0..3

    // ---- stage embedding into LDS (coalesced float4) ----
    {
        const float4* src = (const float4*)emb;
        float4* dst = (float4*)e_lds;
        #pragma unroll
        for (int i = 0; i < 8; ++i) dst[tid + i * BLOCK_T] = src[tid + i * BLOCK_T];
    }
    if (tid < NK) hist[tid] = 0;
    __syncthreads();

    // ---- |e_k|^2 ----
    if (tid < NK) {
        const float4* er = (const float4*)(e_lds + tid * ND);
        float s0 = 0.f, s1 = 0.f, s2 = 0.f, s3 = 0.f;
        #pragma unroll
        for (int j = 0; j < ND / 4; ++j) {
            float4 v = er[j];
            s0 += v.x * v.x; s1 += v.y * v.y; s2 += v.z * v.z; s3 += v.w * v.w;
        }
        eknorm[tid] = (s0 + s1) + (s2 + s3);
    }
    __syncthreads();

    // ---- load my row into registers ----
    const int row = blockIdx.x * ROWS_PER_BLOCK + r;
    float4 xr[16];
    const float4* xp = (const float4*)(x + (size_t)row * ND);
    #pragma unroll
    for (int j = 0; j < 16; ++j) xr[j] = xp[j];

    float xn0 = 0.f, xn1 = 0.f, xn2 = 0.f, xn3 = 0.f;
    #pragma unroll
    for (int j = 0; j < 16; ++j) {
        xn0 += xr[j].x * xr[j].x; xn1 += xr[j].y * xr[j].y;
        xn2 += xr[j].z * xr[j].z; xn3 += xr[j].w * xr[j].w;
    }
    const float xnorm = (xn0 + xn1) + (xn2 + xn3);

    // ---- argmin over my 128-code tile; dist = |e|^2 - 2 x.e ----
    float dmin = INFINITY;
    int amin = tile * 128;
    const int kend = tile * 128 + 128;
    for (int k = tile * 128; k < kend; k += 2) {
        const float4* e0 = (const float4*)(e_lds + k * ND);
        const float4* e1 = (const float4*)(e_lds + (k + 1) * ND);
        float a0 = 0.f, a1 = 0.f, a2 = 0.f, a3 = 0.f;
        float b0 = 0.f, b1 = 0.f, b2 = 0.f, b3 = 0.f;
        #pragma unroll
        for (int j = 0; j < 16; ++j) {
            float4 xv = xr[j];
            float4 v0 = e0[j];
            float4 v1 = e1[j];
            a0 += xv.x * v0.x; a1 += xv.y * v0.y; a2 += xv.z * v0.z; a3 += xv.w * v0.w;
            b0 += xv.x * v1.x; b1 += xv.y * v1.y; b2 += xv.z * v1.z; b3 += xv.w * v1.w;
        }
        float dot0 = (a0 + a1) + (a2 + a3);
        float dot1 = (b0 + b1) + (b2 + b3);
        float d0 = eknorm[k]     - 2.f * dot0;
        float d1 = eknorm[k + 1] - 2.f * dot1;
        if (d0 < dmin) { dmin = d0; amin = k; }       // strict <: first-index tie-break
        if (d1 < dmin) { dmin = d1; amin = k + 1; }
    }
    cand_d[tile * 256 + r] = dmin;
    cand_i[tile * 256 + r] = amin;
    __syncthreads();

    // ---- combine 4 tiles per row (ascending tile order keeps argmin tie-break) ----
    if (tid < 256) {
        float bd = cand_d[tid];
        int   bi = cand_i[tid];
        #pragma unroll
        for (int t = 1; t < 4; ++t) {
            float d = cand_d[t * 256 + tid];
            int   i = cand_i[t * 256 + tid];
            if (d < bd) { bd = d; bi = i; }
        }
        argmin_s[tid] = bi;
        atomicAdd(&hist[bi], 1);

        // loss partial: |x - e_bi|^2 = xnorm + bd  (this thread IS row tid's tile-0 thread)
        float lossv = xnorm + bd;
        #pragma unroll
        for (int off = 32; off >= 1; off >>= 1) lossv += __shfl_down(lossv, off);
        if ((tid & 63) == 0) red[tid >> 6] = lossv;
    }
    __syncthreads();

    if (tid == 0) atomicAdd(g_loss, (red[0] + red[1]) + (red[2] + red[3]));
    if (tid < NK) {
        int c = hist[tid];
        if (c) atomicAdd(&g_counts[tid], c);
    }

    // ---- quantized: coalesced dword stores (region starts at element 1: 4B-aligned) ----
    {
        float* qout = out + Q_OFF + (size_t)blockIdx.x * ROWS_PER_BLOCK * ND;
        #pragma unroll
        for (int it = 0; it < ROWS_PER_BLOCK * ND / BLOCK_T; ++it) {
            int p = tid + it * BLOCK_T;
            int rr = p >> 6;
            int c  = p & 63;
            qout[p] = e_lds[argmin_s[rr] * ND + c];
        }
    }

    // ---- encodings: one-hot rows, coalesced vfloat2 nontemporal stores (8B-aligned) ----
    {
        vfloat2* eout = (vfloat2*)(out + ENC_OFF + (size_t)blockIdx.x * ROWS_PER_BLOCK * NK);
        const int nf2 = ROWS_PER_BLOCK * NK / 2;   // 65536
        for (int p = tid; p < nf2; p += BLOCK_T) {
            int rr = p >> 8;         // 256 vfloat2 per row
            int c2 = p & 255;
            int am = argmin_s[rr];
            vfloat2 v = {0.f, 0.f};
            if ((am >> 1) == c2) {
                if (am & 1) v.y = 1.f; else v.x = 1.f;
            }
            __builtin_nontemporal_store(v, &eout[p]);
        }
    }
}

__global__ __launch_bounds__(512) void vq_final(const int* __restrict__ g_counts,
                                                const float* __restrict__ g_loss,
                                                float* __restrict__ out) {
    __shared__ float red[8];
    int t = threadIdx.x;
    float p = (float)g_counts[t] * (1.0f / (float)NROWS);
    float h = p * logf(p + 1e-10f);
    #pragma unroll
    for (int off = 32; off >= 1; off >>= 1) h += __shfl_down(h, off);
    if ((t & 63) == 0) red[t >> 6] = h;
    __syncthreads();
    if (t == 0) {
        float s = 0.f;
        #pragma unroll
        for (int i = 0; i < 8; ++i) s += red[i];
        out[PERP_OFF] = expf(-s);
        out[0] = 0.25f * g_loss[0] / (float)(NROWS * ND);
    }
}

extern "C" void kernel_launch(void* const* d_in, const int* in_sizes, int n_in,
                              void* d_out, int out_size, void* d_ws, size_t ws_size,
                              hipStream_t stream) {
    const float* x   = (const float*)d_in[0];
    const float* emb = (const float*)d_in[1];
    float* out = (float*)d_out;

    int*   g_counts = (int*)d_ws;
    float* g_loss   = (float*)((char*)d_ws + 2048);

    // ws is re-poisoned to 0xAA before every launch — zero our accumulators.
    (void)hipMemsetAsync(d_ws, 0, 4096, stream);

    // 128KB embedding + norms + 4x256 candidates (d+i) + argmin + hist + red
    size_t lds_bytes = (size_t)(NK * ND + NK        // e_lds + eknorm
                                + 4 * 256 + 4 * 256 // cand_d + cand_i
                                + ROWS_PER_BLOCK    // argmin_s
                                + NK + 16) * 4;     // hist + red
    (void)hipFuncSetAttribute((const void*)vq_main,
                              hipFuncAttributeMaxDynamicSharedMemorySize, (int)lds_bytes);

    vq_main<<<NBLOCKS, BLOCK_T, lds_bytes, stream>>>(x, emb, out, g_counts, g_loss);
    vq_final<<<1, 512, 0, stream>>>(g_counts, g_loss, out);
}